// Round 1
// baseline (308.031 us; speedup 1.0000x reference)
//
#include <hip/hip_runtime.h>

// LBP block fused kernel.
// out[n, 0:3, :, :]   = x
// out[n, 3+o, h, w]   = sum_l exp(w[o,l]) * [y(n,o,h,w) > y(n,o,h+dy_l,w+dx_l)]  (interior)
//                     = 0 on the h/w border
// y(n,o,h,w) = sum_c x[n,c,h,w]*conv_w[o,c], computed sequentially without FMA
// to match numpy's einsum rounding (heaviside compare is bit-sensitive).

__global__ __launch_bounds__(256) void lbp_kernel(
    const float* __restrict__ x,
    const float* __restrict__ conv_w,
    const float* __restrict__ w,
    float* __restrict__ out)
{
#pragma clang fp contract(off)
    const int n   = blockIdx.z;
    const int ch  = blockIdx.y;
    const int tid = threadIdx.x;
    const int h   = blockIdx.x * 4 + (tid >> 6);   // 4 rows per block
    const int wq  = (tid & 63) * 4;                // 4 pixels per thread

    float* outp = out + ((((size_t)n * 67 + ch) * 256 + h) * 256 + wq);

    if (ch < 3) {
        // straight copy of x into the first 3 output channels
        const float4 v = *(const float4*)(x + ((((size_t)n * 3 + ch) * 256 + h) * 256 + wq));
        *(float4*)outp = v;
        return;
    }

    const int o = ch - 3;
    __shared__ float ew[8];
    if (tid < 8) ew[tid] = expf(w[o * 8 + tid]);
    __syncthreads();

    if (h == 0 || h == 255) {
        *(float4*)outp = make_float4(0.f, 0.f, 0.f, 0.f);
        return;
    }

    const float cw0 = conv_w[o * 3 + 0];
    const float cw1 = conv_w[o * 3 + 1];
    const float cw2 = conv_w[o * 3 + 2];

    // y[r][cc] = conv output at (row h-1+r, col wq-1+cc), cc = 0..5
    // Edge columns are clamped; their values are only consumed by border
    // pixels which are overwritten with 0 anyway.
    const int cl = (wq == 0)   ? 0   : wq - 1;
    const int cr = (wq == 252) ? 255 : wq + 4;

    float y[3][6];
    #pragma unroll
    for (int r = 0; r < 3; ++r) {
        const int row = h - 1 + r;
        {
            const float* bp = x + ((((size_t)n * 3 + 0) * 256 + row) * 256);
            const float4 f4 = *(const float4*)(bp + wq);
            y[r][0] = bp[cl] * cw0;
            y[r][1] = f4.x  * cw0;
            y[r][2] = f4.y  * cw0;
            y[r][3] = f4.z  * cw0;
            y[r][4] = f4.w  * cw0;
            y[r][5] = bp[cr] * cw0;
        }
        {
            const float* bp = x + ((((size_t)n * 3 + 1) * 256 + row) * 256);
            const float4 f4 = *(const float4*)(bp + wq);
            y[r][0] += bp[cl] * cw1;
            y[r][1] += f4.x  * cw1;
            y[r][2] += f4.y  * cw1;
            y[r][3] += f4.z  * cw1;
            y[r][4] += f4.w  * cw1;
            y[r][5] += bp[cr] * cw1;
        }
        {
            const float* bp = x + ((((size_t)n * 3 + 2) * 256 + row) * 256);
            const float4 f4 = *(const float4*)(bp + wq);
            y[r][0] += bp[cl] * cw2;
            y[r][1] += f4.x  * cw2;
            y[r][2] += f4.y  * cw2;
            y[r][3] += f4.z  * cw2;
            y[r][4] += f4.w  * cw2;
            y[r][5] += bp[cr] * cw2;
        }
    }

    float res[4];
    #pragma unroll
    for (int j = 0; j < 4; ++j) {
        const int wcol = wq + j;
        if (wcol == 0 || wcol == 255) { res[j] = 0.f; continue; }
        const float c = y[1][j + 1];
        // accumulate in the reference's l = 0..7 order (adds of exact 0.0f
        // preserve bit-exactness of the partial sums)
        float acc;
        acc  = (c > y[0][j    ]) ? ew[0] : 0.f;   // (-1,-1)
        acc += (c > y[0][j + 1]) ? ew[1] : 0.f;   // (-1, 0)
        acc += (c > y[0][j + 2]) ? ew[2] : 0.f;   // (-1,+1)
        acc += (c > y[1][j    ]) ? ew[3] : 0.f;   // ( 0,-1)
        acc += (c > y[2][j    ]) ? ew[4] : 0.f;   // (+1,-1)
        acc += (c > y[2][j + 1]) ? ew[5] : 0.f;   // (+1, 0)
        acc += (c > y[2][j + 2]) ? ew[6] : 0.f;   // (+1,+1)
        acc += (c > y[1][j + 2]) ? ew[7] : 0.f;   // ( 0,+1)
        res[j] = acc;
    }
    *(float4*)outp = make_float4(res[0], res[1], res[2], res[3]);
}

extern "C" void kernel_launch(void* const* d_in, const int* in_sizes, int n_in,
                              void* d_out, int out_size, void* d_ws, size_t ws_size,
                              hipStream_t stream) {
    const float* x      = (const float*)d_in[0];
    const float* conv_w = (const float*)d_in[1];
    const float* w      = (const float*)d_in[2];
    float* out          = (float*)d_out;

    dim3 grid(64, 67, 8);   // (row-groups of 4, channels, batch)
    dim3 block(256);
    hipLaunchKernelGGL(lbp_kernel, grid, block, 0, stream, x, conv_w, w, out);
}

// Round 2
// 158.481 us; speedup vs baseline: 1.9436x; 1.9436x over previous
//
#include <hip/hip_runtime.h>

// LBP block fused kernels.
// out[n, 0:3]  = x                       (copy_x_kernel)
// out[n, 3+o]  = LBP response, zero border  (lbp_kernel)
//
// Numerics: y = (x0*cw0 + x1*cw1) + x2*cw2 computed sequentially with FMA
// contraction OFF to match the numpy reference bit-for-bit; heaviside
// (c - s > 0) == (c > s) exactly for finite floats. y is computed ONCE per
// (n,o,row,col) into LDS so every consumer sees the identical value.

__global__ __launch_bounds__(256) void copy_x_kernel(
    const float* __restrict__ x, float* __restrict__ out)
{
    const int n   = blockIdx.z;
    const int c   = blockIdx.y;
    const int tid = threadIdx.x;
    const int h   = blockIdx.x * 4 + (tid >> 6);
    const int wq  = (tid & 63) * 4;
    const float4 v = *(const float4*)(x + ((((size_t)n * 3 + c) * 256 + h) * 256 + wq));
    *(float4*)(out + ((((size_t)n * 67 + c) * 256 + h) * 256 + wq)) = v;
}

__global__ __launch_bounds__(256) void lbp_kernel(
    const float* __restrict__ x,
    const float* __restrict__ conv_w,
    const float* __restrict__ w,
    float* __restrict__ out)
{
#pragma clang fp contract(off)
    const int n    = blockIdx.z;
    const int o    = blockIdx.y;
    const int h0   = blockIdx.x * 8;       // 8 output rows per block
    const int tid  = threadIdx.x;
    const int lane = tid & 63;
    const int wv   = tid >> 6;             // wave id 0..3

    __shared__ float ylds[10][256];        // y rows h0-1 .. h0+8 (clamped)
    __shared__ float ews[8];

    if (tid < 8) ews[tid] = expf(w[o * 8 + tid]);

    const float cw0 = conv_w[o * 3 + 0];
    const float cw1 = conv_w[o * 3 + 1];
    const float cw2 = conv_w[o * 3 + 2];
    const float* xn = x + (size_t)n * 3 * 256 * 256;
    const int col = lane * 4;

    // ---- Phase 1: y rows into LDS (each y value computed exactly once) ----
    #pragma unroll
    for (int p = 0; p < 3; ++p) {
        const int i = p * 4 + wv;          // LDS row index 0..11 (10,11 unused)
        if (i < 10) {
            int row = h0 - 1 + i;
            row = row < 0 ? 0 : (row > 255 ? 255 : row);
            const float4 a = *(const float4*)(xn + (0 * 256 + row) * 256 + col);
            const float4 b = *(const float4*)(xn + (1 * 256 + row) * 256 + col);
            const float4 c = *(const float4*)(xn + (2 * 256 + row) * 256 + col);
            float4 yv;
            yv.x = a.x * cw0 + b.x * cw1 + c.x * cw2;
            yv.y = a.y * cw0 + b.y * cw1 + c.y * cw2;
            yv.z = a.z * cw0 + b.z * cw1 + c.z * cw2;
            yv.w = a.w * cw0 + b.w * cw1 + c.w * cw2;
            *(float4*)&ylds[i][col] = yv;
        }
    }
    __syncthreads();

    // ---- Phase 2: compares from LDS; wave wv owns output rows h0+2wv, h0+2wv+1
    const float e0 = ews[0], e1 = ews[1], e2 = ews[2], e3 = ews[3];
    const float e4 = ews[4], e5 = ews[5], e6 = ews[6], e7 = ews[7];

    // Y[r][k] = y at LDS row (2wv + r), col (4*lane - 1 + k), k=0..5.
    // Halo cols come from neighbor lanes via shuffle; lane-0/63 halo garbage
    // feeds only border pixels which are zeroed.
    float Y[4][6];
    #pragma unroll
    for (int r = 0; r < 4; ++r) {
        const float4 v = *(const float4*)&ylds[2 * wv + r][col];
        Y[r][1] = v.x; Y[r][2] = v.y; Y[r][3] = v.z; Y[r][4] = v.w;
        Y[r][0] = __shfl_up(v.w, 1);
        Y[r][5] = __shfl_down(v.x, 1);
    }

    float* outp = out + ((((size_t)n * 67 + 3 + o) * 256 + h0) * 256);

    #pragma unroll
    for (int jr = 0; jr < 2; ++jr) {
        const int hrow = h0 + 2 * wv + jr;
        float res[4];
        if (hrow == 0 || hrow == 255) {
            res[0] = res[1] = res[2] = res[3] = 0.f;
        } else {
            const float* up = Y[jr];
            const float* mid = Y[jr + 1];
            const float* dn = Y[jr + 2];
            #pragma unroll
            for (int j = 0; j < 4; ++j) {
                const int cidx = col + j;
                if ((cidx == 0) | (cidx == 255)) { res[j] = 0.f; continue; }
                const float c = mid[j + 1];
                float acc;
                acc  = (c > up [j    ]) ? e0 : 0.f;   // (-1,-1)
                acc += (c > up [j + 1]) ? e1 : 0.f;   // (-1, 0)
                acc += (c > up [j + 2]) ? e2 : 0.f;   // (-1,+1)
                acc += (c > mid[j    ]) ? e3 : 0.f;   // ( 0,-1)
                acc += (c > dn [j    ]) ? e4 : 0.f;   // (+1,-1)
                acc += (c > dn [j + 1]) ? e5 : 0.f;   // (+1, 0)
                acc += (c > dn [j + 2]) ? e6 : 0.f;   // (+1,+1)
                acc += (c > mid[j + 2]) ? e7 : 0.f;   // ( 0,+1)
                res[j] = acc;
            }
        }
        *(float4*)(outp + (size_t)(2 * wv + jr) * 256 + col) =
            make_float4(res[0], res[1], res[2], res[3]);
    }
}

extern "C" void kernel_launch(void* const* d_in, const int* in_sizes, int n_in,
                              void* d_out, int out_size, void* d_ws, size_t ws_size,
                              hipStream_t stream) {
    const float* x      = (const float*)d_in[0];
    const float* conv_w = (const float*)d_in[1];
    const float* w      = (const float*)d_in[2];
    float* out          = (float*)d_out;

    hipLaunchKernelGGL(copy_x_kernel, dim3(64, 3, 8), dim3(256), 0, stream, x, out);
    hipLaunchKernelGGL(lbp_kernel, dim3(32, 64, 8), dim3(256), 0, stream,
                       x, conv_w, w, out);
}